// Round 6
// baseline (1414.280 us; speedup 1.0000x reference)
//
#include <hip/hip_runtime.h>

// Problem constants (reference: N=50000 nodes, E=800000 edges, D=128, K=3)
#define Nn 50000
#define Ee 800000
#define Dd 128
#define Kk 3
#define TE 128   // rows per block tile
#define NT 256   // threads per block (4 waves)

// LDS bf16 tile row stride (ushorts): 128 + 8 pad
#define LSTR 136
// Per-matrix packed-weight slot: hi[16384] + lo[16384] ushorts
#define WSLOT 32768

typedef short sh8 __attribute__((ext_vector_type(8)));    // 8 bf16 (4 VGPRs)
typedef float f32x4 __attribute__((ext_vector_type(4)));  // MFMA C/D

// Split fp32 into bf16 hi (truncate) + bf16 lo (residual, truncate).
__device__ __forceinline__ ushort bfsplit(float x, float* rem) {
  const unsigned u = __float_as_uint(x);
  *rem = x - __uint_as_float(u & 0xffff0000u);
  return (ushort)(u >> 16);
}
__device__ __forceinline__ ushort bftrunc(float x) {
  return (ushort)(__float_as_uint(x) >> 16);
}

// 128x128x128 layer on MFMA 16x16x32_bf16, split-bf16 (3 products).
// Wave w owns cols [32w,32w+32); 8 m-tiles; acc[8][2].
// A frag: lane reads A[m=lane&15][k=(lane>>4)*8+j]  (ds_read_b128 from Sh/Sl)
// B frag: packed global, [((nt*4+c)*64+lane)*8+j]
#define MFMA_LAYER(WH, WL)                                                     \
  {                                                                            \
    _Pragma("unroll")                                                          \
    for (int c = 0; c < 4; ++c) {                                              \
      const sh8 bh0 = *(const sh8*)((WH) + (((nt0    ) * 4 + c) * 64 + lane) * 8); \
      const sh8 bh1 = *(const sh8*)((WH) + (((nt0 + 1) * 4 + c) * 64 + lane) * 8); \
      const sh8 bl0 = *(const sh8*)((WL) + (((nt0    ) * 4 + c) * 64 + lane) * 8); \
      const sh8 bl1 = *(const sh8*)((WL) + (((nt0 + 1) * 4 + c) * 64 + lane) * 8); \
      _Pragma("unroll")                                                        \
      for (int mt = 0; mt < 8; ++mt) {                                         \
        const int aoff = (mt * 16 + l15) * LSTR + c * 32 + q8 * 8;             \
        const sh8 ah = *(const sh8*)(Sh + aoff);                               \
        const sh8 al = *(const sh8*)(Sl + aoff);                               \
        acc[mt][0] = __builtin_amdgcn_mfma_f32_16x16x32_bf16(ah, bh0, acc[mt][0], 0, 0, 0); \
        acc[mt][1] = __builtin_amdgcn_mfma_f32_16x16x32_bf16(ah, bh1, acc[mt][1], 0, 0, 0); \
        acc[mt][0] = __builtin_amdgcn_mfma_f32_16x16x32_bf16(al, bh0, acc[mt][0], 0, 0, 0); \
        acc[mt][1] = __builtin_amdgcn_mfma_f32_16x16x32_bf16(al, bh1, acc[mt][1], 0, 0, 0); \
        acc[mt][0] = __builtin_amdgcn_mfma_f32_16x16x32_bf16(ah, bl0, acc[mt][0], 0, 0, 0); \
        acc[mt][1] = __builtin_amdgcn_mfma_f32_16x16x32_bf16(ah, bl1, acc[mt][1], 0, 0, 0); \
      }                                                                        \
    }                                                                          \
  }

#define ZERO_ACC                                                 \
  {                                                              \
    _Pragma("unroll")                                            \
    for (int mt = 0; mt < 8; ++mt)                               \
      _Pragma("unroll")                                          \
      for (int nl = 0; nl < 2; ++nl) {                           \
        acc[mt][nl][0] = 0.f; acc[mt][nl][1] = 0.f;              \
        acc[mt][nl][2] = 0.f; acc[mt][nl][3] = 0.f;              \
      }                                                          \
  }

// hidden = relu(acc + b1) -> split hi/lo back into LDS (C layout -> A layout)
#define HIDDEN_TO_LDS(B1ptr)                                     \
  {                                                              \
    const float b1a = (B1ptr)[w32 + l15];                        \
    const float b1b = (B1ptr)[w32 + 16 + l15];                   \
    _Pragma("unroll")                                            \
    for (int mt = 0; mt < 8; ++mt)                               \
      _Pragma("unroll")                                          \
      for (int nl = 0; nl < 2; ++nl) {                           \
        const int col = w32 + nl * 16 + l15;                     \
        const float bb = nl ? b1b : b1a;                         \
        _Pragma("unroll")                                        \
        for (int rg = 0; rg < 4; ++rg) {                         \
          const int row = mt * 16 + q8 * 4 + rg;                 \
          const float h = fmaxf(acc[mt][nl][rg] + bb, 0.f);      \
          float rm;                                              \
          const ushort hh = bfsplit(h, &rm);                     \
          const int off = row * LSTR + col;                      \
          Sh[off] = hh;                                          \
          Sl[off] = bftrunc(rm);                                 \
        }                                                        \
      }                                                          \
  }

// stage rows [row0, row0+nrow) of row-major X (stride Dd) into Sh/Sl split
#define STAGE_ROWS(Xptr)                                                       \
  {                                                                            \
    _Pragma("unroll")                                                          \
    for (int it = 0; it < 16; ++it) {                                          \
      const int i = t + NT * it;                                               \
      const int r = i >> 5;                                                    \
      const int c4 = (i & 31) << 2;                                            \
      float4 v = make_float4(0.f, 0.f, 0.f, 0.f);                              \
      if (r < nrow) v = *(const float4*)((Xptr) + (size_t)(row0 + r) * Dd + c4); \
      ushort4 hv, lv; float rm;                                                \
      hv.x = bfsplit(v.x, &rm); lv.x = bftrunc(rm);                            \
      hv.y = bfsplit(v.y, &rm); lv.y = bftrunc(rm);                            \
      hv.z = bfsplit(v.z, &rm); lv.z = bftrunc(rm);                            \
      hv.w = bfsplit(v.w, &rm); lv.w = bftrunc(rm);                            \
      *(ushort4*)(&Sh[r * LSTR + c4]) = hv;                                    \
      *(ushort4*)(&Sl[r * LSTR + c4]) = lv;                                    \
    }                                                                          \
  }

#define MFMA_PRELUDE                                             \
  const int lane = t & 63;                                       \
  const int wave = t >> 6;                                       \
  const int l15 = lane & 15;                                     \
  const int q8 = lane >> 4;                                      \
  const int w32 = wave * 32;                                     \
  const int nt0 = wave * 2;                                      \
  f32x4 acc[8][2];

// Per-direction parameter pack: packed hi bases (lo = +16384) + biases.
struct DirP {
  const ushort *u1, *u2, *p1, *p2;             // upd w1/w2, msg w1/w2 (packed)
  const float *ub1, *ub2, *pb1, *pb2;
};

// ---------------------------------------------------------------------------
// st = fnn(feat; nt), no final relu. Single direction, 391 blocks.
// ---------------------------------------------------------------------------
__global__ __launch_bounds__(NT) void st_kernel(
    const float* __restrict__ X,
    const ushort* __restrict__ W1, const ushort* __restrict__ W2,
    const float* __restrict__ B1, const float* __restrict__ B2,
    float* __restrict__ out)
{
  __shared__ __align__(16) ushort Sbuf[2 * TE * LSTR];  // 69.6 KB
  ushort* Sh = Sbuf;
  ushort* Sl = Sbuf + TE * LSTR;
  const int t = threadIdx.x;
  const int row0 = blockIdx.x * TE;
  const int rem = Nn - row0;
  const int nrow = rem < TE ? rem : TE;

  STAGE_ROWS(X);
  __syncthreads();
  MFMA_PRELUDE;
  ZERO_ACC;
  MFMA_LAYER(W1, W1 + 16384);
  __syncthreads();
  HIDDEN_TO_LDS(B1);
  __syncthreads();
  ZERO_ACC;
  MFMA_LAYER(W2, W2 + 16384);

  const float b2a = B2[w32 + l15];
  const float b2b = B2[w32 + 16 + l15];
  #pragma unroll
  for (int mt = 0; mt < 8; ++mt)
    #pragma unroll
    for (int nl = 0; nl < 2; ++nl) {
      const int col = w32 + nl * 16 + l15;
      const float bb = nl ? b2b : b2a;
      #pragma unroll
      for (int rg = 0; rg < 4; ++rg) {
        const int row = mt * 16 + q8 * 4 + rg;
        if (row < nrow)
          out[(size_t)(row0 + row) * Dd + col] = acc[mt][nl][rg] + bb;
      }
    }
}

// ---------------------------------------------------------------------------
// Round-1 msg: M = relu(fnn(st; p)) per direction. Dual grid (2*391 blocks).
// ---------------------------------------------------------------------------
__global__ __launch_bounds__(NT) void msg0_kernel(
    const float* __restrict__ st,
    float* __restrict__ Mf, float* __restrict__ Mb, int mstride,
    DirP pf, DirP pb, int nhalf)
{
  __shared__ __align__(16) ushort Sbuf[2 * TE * LSTR];
  ushort* Sh = Sbuf;
  ushort* Sl = Sbuf + TE * LSTR;
  const int t = threadIdx.x;
  const int dir = blockIdx.x >= nhalf;
  const int row0 = (blockIdx.x - dir * nhalf) * TE;
  const int rem = Nn - row0;
  const int nrow = rem < TE ? rem : TE;
  const DirP P = dir ? pb : pf;
  float* Mout = dir ? Mb : Mf;

  STAGE_ROWS(st);
  __syncthreads();
  MFMA_PRELUDE;
  ZERO_ACC;
  MFMA_LAYER(P.p1, P.p1 + 16384);
  __syncthreads();
  HIDDEN_TO_LDS(P.pb1);
  __syncthreads();
  ZERO_ACC;
  MFMA_LAYER(P.p2, P.p2 + 16384);

  const float b2a = P.pb2[w32 + l15];
  const float b2b = P.pb2[w32 + 16 + l15];
  #pragma unroll
  for (int mt = 0; mt < 8; ++mt)
    #pragma unroll
    for (int nl = 0; nl < 2; ++nl) {
      const int col = w32 + nl * 16 + l15;
      const float bb = nl ? b2b : b2a;
      #pragma unroll
      for (int rg = 0; rg < 4; ++rg) {
        const int row = mt * 16 + q8 * 4 + rg;
        if (row < nrow)
          Mout[(size_t)(row0 + row) * mstride + col] =
              fmaxf(acc[mt][nl][rg] + bb, 0.f);
      }
    }
}

// ---------------------------------------------------------------------------
// Fused per-round kernel, dual direction (2*391 blocks):
//   z-tile  = CSR gather-sum of Min rows            (atomic-free, exclusive)
//   y-tile  = st + relu(fnn(z; u)), y[sink] handling
//   DO_MSG:   M' = relu(fnn(y; p)) -> Rout          (rounds 1,2)
//   !DO_MSG:  y -> Rout                             (final round -> d_out)
//
// Phase A (gather) is half-wave coalesced: 32 lanes read one M row as
// 32 x 16 B contiguous (8 fully-used 64B sectors); lane l owns cols 4l..4l+3.
// Edge loop unrolled x4 for 4 outstanding loads per lane.
// ---------------------------------------------------------------------------
template <int DO_MSG>
__global__ __launch_bounds__(NT) void aggupdmsg_kernel(
    const float* __restrict__ Min_f, const float* __restrict__ Min_b, int min_stride,
    const int* __restrict__ rp_f, const int* __restrict__ rp_b,
    const int* __restrict__ col_f, const int* __restrict__ col_b,
    const float* __restrict__ st,
    float* __restrict__ Rf, float* __restrict__ Rb, int rstride,
    DirP pf, DirP pb, int nhalf)
{
  __shared__ __align__(16) ushort Sbuf[2 * TE * LSTR];
  ushort* Sh = Sbuf;
  ushort* Sl = Sbuf + TE * LSTR;
  const int t = threadIdx.x;
  const int dir = blockIdx.x >= nhalf;
  const int row0 = (blockIdx.x - dir * nhalf) * TE;
  const int rem = Nn - row0;
  const int nrow = rem < TE ? rem : TE;
  const DirP P = dir ? pb : pf;
  const float* Min = dir ? Min_b : Min_f;
  const int* rp = dir ? rp_b : rp_f;
  const int* col = dir ? col_b : col_f;
  float* Rout = dir ? Rb : Rf;
  const int sink = dir ? 0 : (Nn - 1);

  // ---- phase A: half-wave-coalesced gather-sum of z rows ----
  {
    const int hw = t >> 5;          // half-wave 0..7
    const int l4 = (t & 31) << 2;   // this lane's 4 columns
    #pragma unroll 1
    for (int rr = 0; rr < 16; ++rr) {
      const int nr = hw * 16 + rr;  // tile row
      float4 za = make_float4(0.f, 0.f, 0.f, 0.f);
      if (nr < nrow) {
        const int gnode = row0 + nr;
        int e = rp[gnode];
        const int ee = rp[gnode + 1];
        for (; e + 3 < ee; e += 4) {   // 4 rows in flight, fully coalesced
          const float4 v0 = *(const float4*)(Min + (size_t)col[e]     * min_stride + l4);
          const float4 v1 = *(const float4*)(Min + (size_t)col[e + 1] * min_stride + l4);
          const float4 v2 = *(const float4*)(Min + (size_t)col[e + 2] * min_stride + l4);
          const float4 v3 = *(const float4*)(Min + (size_t)col[e + 3] * min_stride + l4);
          za.x += (v0.x + v1.x) + (v2.x + v3.x);
          za.y += (v0.y + v1.y) + (v2.y + v3.y);
          za.z += (v0.z + v1.z) + (v2.z + v3.z);
          za.w += (v0.w + v1.w) + (v2.w + v3.w);
        }
        for (; e < ee; ++e) {
          const float4 v0 = *(const float4*)(Min + (size_t)col[e] * min_stride + l4);
          za.x += v0.x; za.y += v0.y; za.z += v0.z; za.w += v0.w;
        }
      }
      ushort4 hv, lv; float rm;
      hv.x = bfsplit(za.x, &rm); lv.x = bftrunc(rm);
      hv.y = bfsplit(za.y, &rm); lv.y = bftrunc(rm);
      hv.z = bfsplit(za.z, &rm); lv.z = bftrunc(rm);
      hv.w = bfsplit(za.w, &rm); lv.w = bftrunc(rm);
      *(ushort4*)(&Sh[nr * LSTR + l4]) = hv;
      *(ushort4*)(&Sl[nr * LSTR + l4]) = lv;
    }
  }
  __syncthreads();

  MFMA_PRELUDE;

  // ---- phase B: update MLP ----
  ZERO_ACC;
  MFMA_LAYER(P.u1, P.u1 + 16384);
  __syncthreads();
  HIDDEN_TO_LDS(P.ub1);
  __syncthreads();
  ZERO_ACC;
  MFMA_LAYER(P.u2, P.u2 + 16384);

  // y = st + relu(acc + ub2), y[sink-row contribution] zeroed
  {
    const float b2a = P.ub2[w32 + l15];
    const float b2b = P.ub2[w32 + 16 + l15];
    if (DO_MSG) __syncthreads();  // all hidden reads done before overwrite
    #pragma unroll
    for (int mt = 0; mt < 8; ++mt)
      #pragma unroll
      for (int nl = 0; nl < 2; ++nl) {
        const int col = w32 + nl * 16 + l15;
        const float bb = nl ? b2b : b2a;
        #pragma unroll
        for (int rg = 0; rg < 4; ++rg) {
          const int row = mt * 16 + q8 * 4 + rg;
          float v = 0.f;
          if (row < nrow) {
            const int gr = row0 + row;
            v = fmaxf(acc[mt][nl][rg] + bb, 0.f);
            if (gr == sink) v = 0.f;
            v += st[(size_t)gr * Dd + col];
          }
          if (DO_MSG) {
            float rm;
            const ushort hh = bfsplit(v, &rm);
            const int off = row * LSTR + col;
            Sh[off] = hh;
            Sl[off] = bftrunc(rm);
          } else if (row < nrow) {
            Rout[(size_t)(row0 + row) * rstride + col] = v;
          }
        }
      }
  }

  if (DO_MSG) {
    __syncthreads();
    // ---- phase C: msg MLP on y-tile ----
    ZERO_ACC;
    MFMA_LAYER(P.p1, P.p1 + 16384);
    __syncthreads();
    HIDDEN_TO_LDS(P.pb1);
    __syncthreads();
    ZERO_ACC;
    MFMA_LAYER(P.p2, P.p2 + 16384);

    const float b2a = P.pb2[w32 + l15];
    const float b2b = P.pb2[w32 + 16 + l15];
    #pragma unroll
    for (int mt = 0; mt < 8; ++mt)
      #pragma unroll
      for (int nl = 0; nl < 2; ++nl) {
        const int col = w32 + nl * 16 + l15;
        const float bb = nl ? b2b : b2a;
        #pragma unroll
        for (int rg = 0; rg < 4; ++rg) {
          const int row = mt * 16 + q8 * 4 + rg;
          if (row < nrow)
            Rout[(size_t)(row0 + row) * rstride + col] =
                fmaxf(acc[mt][nl][rg] + bb, 0.f);
        }
      }
  }
}

// ---------------------------------------------------------------------------
// Weight packing: matrices -> B-fragment order, split hi/lo.
// Slot = WSLOT ushorts: hi[16384], lo[16384]. id = ((nt*4+ch)*64+lane)*8+j
// maps to W[k][n]: k = ch*32+(lane>>4)*8+j, n = nt*16+(lane&15).
// ---------------------------------------------------------------------------
struct WPtrs { const float* w[10]; };

__global__ void pack_w_kernel(WPtrs P, ushort* __restrict__ out)
{
  const int id = blockIdx.x * blockDim.x + threadIdx.x;  // 0..16383
  const int mat = blockIdx.y;
  const int j = id & 7;
  const int lane = (id >> 3) & 63;
  const int ch = (id >> 9) & 3;
  const int nt = id >> 11;
  const int k = ch * 32 + (lane >> 4) * 8 + j;
  const int n = nt * 16 + (lane & 15);
  const float x = P.w[mat][k * Dd + n];
  float rm;
  const ushort h = bfsplit(x, &rm);
  out[(size_t)mat * WSLOT + id] = h;
  out[(size_t)mat * WSLOT + 16384 + id] = bftrunc(rm);
}

// ---------------------------------------------------------------------------
// CSR build: histogram -> single-block scan (x2, cur aliases deg) -> fill
// ---------------------------------------------------------------------------
__global__ void hist_kernel(const int* __restrict__ src, const int* __restrict__ dst,
                            int* __restrict__ deg_f, int* __restrict__ deg_b, int e)
{
  const int i = blockIdx.x * blockDim.x + threadIdx.x;
  if (i < e) {
    atomicAdd(&deg_f[dst[i]], 1);
    atomicAdd(&deg_b[src[i]], 1);
  }
}

__global__ __launch_bounds__(1024) void scan_kernel(
    const int* deg0, int* rp0, int* cur0,
    const int* deg1, int* rp1, int* cur1, int n)
{
  const int* deg = blockIdx.x ? deg1 : deg0;
  int* rp  = blockIdx.x ? rp1  : rp0;
  int* cur = blockIdx.x ? cur1 : cur0;
  __shared__ int a[1024], b[1024];
  const int t = threadIdx.x;
  int run = 0;
  for (int base = 0; base < n; base += 1024) {
    const int v = (base + t < n) ? deg[base + t] : 0;
    a[t] = v;
    __syncthreads();
    int* s = a; int* d = b;
    for (int off = 1; off < 1024; off <<= 1) {
      int x = s[t];
      if (t >= off) x += s[t - off];
      d[t] = x;
      __syncthreads();
      int* tmp = s; s = d; d = tmp;
    }
    const int incl = s[t];
    const int tot = s[1023];
    if (base + t < n) { rp[base + t] = run + incl - v; cur[base + t] = run + incl - v; }
    run += tot;
    __syncthreads();
  }
  if (t == 0) rp[n] = run;
}

// forward: col_f (src values) grouped by dst; backward: col_b (dst values)
// grouped by src. (reference backward pass gathers y[dst], scatters to src)
__global__ void fill_kernel(const int* __restrict__ src, const int* __restrict__ dst,
                            int* __restrict__ cur_f, int* __restrict__ cur_b,
                            int* __restrict__ col_f, int* __restrict__ col_b, int e)
{
  const int i = blockIdx.x * blockDim.x + threadIdx.x;
  if (i < e) {
    const int s = src[i], d = dst[i];
    col_f[atomicAdd(&cur_f[d], 1)] = s;
    col_b[atomicAdd(&cur_b[s], 1)] = d;
  }
}

// ---------------------------------------------------------------------------
extern "C" void kernel_launch(void* const* d_in, const int* in_sizes, int n_in,
                              void* d_out, int out_size, void* d_ws, size_t ws_size,
                              hipStream_t stream)
{
  const float* feat = (const float*)d_in[0];
  const int*   src  = (const int*)d_in[1];
  const int*   dst  = (const int*)d_in[2];

  const float* W[5][4];
  for (int p = 0; p < 5; ++p)
    for (int q = 0; q < 4; ++q)
      W[p][q] = (const float*)d_in[3 + p * 4 + q];

  // workspace (~85 MB): st + M-ping (f,b) + CSR + packed weights.
  // M-pong lives in d_out's two column-halves (row stride 2*Dd).
  float* st   = (float*)d_ws;                   // [N,D]
  float* Mp_f = st + (size_t)Nn * Dd;           // ping fwd [N,D]
  float* Mp_b = Mp_f + (size_t)Nn * Dd;         // ping bwd [N,D]
  int* ip       = (int*)(Mp_b + (size_t)Nn * Dd);
  int* rp_f     = ip;                 ip += Nn + 1;
  int* rp_b     = ip;                 ip += Nn + 1;
  int* deg_f    = ip;                 ip += Nn;   // cur aliases deg
  int* deg_b    = ip;                 ip += Nn;
  int* col_f    = ip;                 ip += Ee;
  int* col_b    = ip;                 ip += Ee;
  ushort* Wp = (ushort*)(((uintptr_t)ip + 63) & ~(uintptr_t)63);  // 640 KB
  float* out = (float*)d_out;                   // [N, 2D]
  float* Mq_f = out;                            // pong fwd: cols 0..127
  float* Mq_b = out + Dd;                       // pong bwd: cols 128..255

  const int nodeBlocks = (Nn + TE - 1) / TE;    // 391
  const int dualBlocks = 2 * nodeBlocks;        // 782
  const int eGrid = (Ee + NT - 1) / NT;

  // ---- pack weights ----
  WPtrs wpk;  // slots: 2p = W[p].w1, 2p+1 = W[p].w2
  for (int p = 0; p < 5; ++p) { wpk.w[2 * p] = W[p][0]; wpk.w[2 * p + 1] = W[p][2]; }
  pack_w_kernel<<<dim3(64, 10), NT, 0, stream>>>(wpk, Wp);

  // ---- CSR build ----
  hipMemsetAsync(deg_f, 0, (size_t)2 * Nn * sizeof(int), stream);
  hist_kernel<<<eGrid, NT, 0, stream>>>(src, dst, deg_f, deg_b, Ee);
  scan_kernel<<<2, 1024, 0, stream>>>(deg_f, rp_f, deg_f, deg_b, rp_b, deg_b, Nn);
  fill_kernel<<<eGrid, NT, 0, stream>>>(src, dst, deg_f, deg_b, col_f, col_b, Ee);

  #define WS(m) (Wp + (size_t)(m) * WSLOT)
  // fwd: upd = fu (p=2), msg = fp (p=1); bwd: upd = bu (p=4), msg = bp (p=3)
  DirP Pf = { WS(4), WS(5), WS(2), WS(3), W[2][1], W[2][3], W[1][1], W[1][3] };
  DirP Pb = { WS(8), WS(9), WS(6), WS(7), W[4][1], W[4][3], W[3][1], W[3][3] };

  // ---- st = fnn(feat; nt) ----
  st_kernel<<<nodeBlocks, NT, 0, stream>>>(feat, WS(0), WS(1), W[0][1], W[0][3], st);

  // ---- round 1 msg from st -> M ping ----
  msg0_kernel<<<dualBlocks, NT, 0, stream>>>(st, Mp_f, Mp_b, Dd, Pf, Pb, nodeBlocks);

  // ---- round 1: agg+upd+msg, ping -> pong(out) ----
  aggupdmsg_kernel<1><<<dualBlocks, NT, 0, stream>>>(
      Mp_f, Mp_b, Dd, rp_f, rp_b, col_f, col_b, st,
      Mq_f, Mq_b, 2 * Dd, Pf, Pb, nodeBlocks);

  // ---- round 2: agg+upd+msg, pong(out) -> ping ----
  aggupdmsg_kernel<1><<<dualBlocks, NT, 0, stream>>>(
      Mq_f, Mq_b, 2 * Dd, rp_f, rp_b, col_f, col_b, st,
      Mp_f, Mp_b, Dd, Pf, Pb, nodeBlocks);

  // ---- round 3 (final): agg+upd, ping -> y into out column-halves ----
  aggupdmsg_kernel<0><<<dualBlocks, NT, 0, stream>>>(
      Mp_f, Mp_b, Dd, rp_f, rp_b, col_f, col_b, st,
      out, out + Dd, 2 * Dd, Pf, Pb, nodeBlocks);

  #undef WS
}

// Round 8
// 1079.736 us; speedup vs baseline: 1.3098x; 1.3098x over previous
//
#include <hip/hip_runtime.h>

// Problem constants (reference: N=50000 nodes, E=800000 edges, D=128, K=3)
#define Nn 50000
#define Ee 800000
#define Dd 128
#define Kk 3
#define TE 128   // rows per block tile
#define NT 256   // threads per block (4 waves)

// LDS bf16 tile row stride (ushorts): 128 + 8 pad
#define LSTR 136
// Per-matrix packed-weight slot: hi[16384] + lo[16384] ushorts
#define WSLOT 32768

typedef short sh8 __attribute__((ext_vector_type(8)));    // 8 bf16 (4 VGPRs)
typedef float f32x4 __attribute__((ext_vector_type(4)));  // MFMA C/D

// Split fp32 into bf16 hi (truncate) + bf16 lo (residual, truncate).
__device__ __forceinline__ ushort bfsplit(float x, float* rem) {
  const unsigned u = __float_as_uint(x);
  *rem = x - __uint_as_float(u & 0xffff0000u);
  return (ushort)(u >> 16);
}
__device__ __forceinline__ ushort bftrunc(float x) {
  return (ushort)(__float_as_uint(x) >> 16);
}
// round-to-nearest f32 -> bf16 (x >= 0, finite)
__device__ __forceinline__ ushort f32_to_bf16_rtn(float x) {
  const unsigned u = __float_as_uint(x);
  return (ushort)((u + 0x7fffu + ((u >> 16) & 1u)) >> 16);
}

// accumulate 8 bf16 packed in one uint4 into two float4 accumulators
__device__ __forceinline__ void acc8(const uint4 v, float4& a0, float4& a1) {
  a0.x += __uint_as_float(v.x << 16);
  a0.y += __uint_as_float(v.x & 0xffff0000u);
  a0.z += __uint_as_float(v.y << 16);
  a0.w += __uint_as_float(v.y & 0xffff0000u);
  a1.x += __uint_as_float(v.z << 16);
  a1.y += __uint_as_float(v.z & 0xffff0000u);
  a1.z += __uint_as_float(v.w << 16);
  a1.w += __uint_as_float(v.w & 0xffff0000u);
}

// 128x128x128 layer on MFMA 16x16x32_bf16, split-bf16 (3 products).
// Wave w owns cols [32w,32w+32); 8 m-tiles; acc[8][2].
// A frag: lane reads A[m=lane&15][k=(lane>>4)*8+j]  (ds_read_b128 from Sh/Sl)
// B frag: packed global, [((nt*4+c)*64+lane)*8+j]
#define MFMA_LAYER(WH, WL)                                                     \
  {                                                                            \
    _Pragma("unroll")                                                          \
    for (int c = 0; c < 4; ++c) {                                              \
      const sh8 bh0 = *(const sh8*)((WH) + (((nt0    ) * 4 + c) * 64 + lane) * 8); \
      const sh8 bh1 = *(const sh8*)((WH) + (((nt0 + 1) * 4 + c) * 64 + lane) * 8); \
      const sh8 bl0 = *(const sh8*)((WL) + (((nt0    ) * 4 + c) * 64 + lane) * 8); \
      const sh8 bl1 = *(const sh8*)((WL) + (((nt0 + 1) * 4 + c) * 64 + lane) * 8); \
      _Pragma("unroll")                                                        \
      for (int mt = 0; mt < 8; ++mt) {                                         \
        const int aoff = (mt * 16 + l15) * LSTR + c * 32 + q8 * 8;             \
        const sh8 ah = *(const sh8*)(Sh + aoff);                               \
        const sh8 al = *(const sh8*)(Sl + aoff);                               \
        acc[mt][0] = __builtin_amdgcn_mfma_f32_16x16x32_bf16(ah, bh0, acc[mt][0], 0, 0, 0); \
        acc[mt][1] = __builtin_amdgcn_mfma_f32_16x16x32_bf16(ah, bh1, acc[mt][1], 0, 0, 0); \
        acc[mt][0] = __builtin_amdgcn_mfma_f32_16x16x32_bf16(al, bh0, acc[mt][0], 0, 0, 0); \
        acc[mt][1] = __builtin_amdgcn_mfma_f32_16x16x32_bf16(al, bh1, acc[mt][1], 0, 0, 0); \
        acc[mt][0] = __builtin_amdgcn_mfma_f32_16x16x32_bf16(ah, bl0, acc[mt][0], 0, 0, 0); \
        acc[mt][1] = __builtin_amdgcn_mfma_f32_16x16x32_bf16(ah, bl1, acc[mt][1], 0, 0, 0); \
      }                                                                        \
    }                                                                          \
  }

#define ZERO_ACC                                                 \
  {                                                              \
    _Pragma("unroll")                                            \
    for (int mt = 0; mt < 8; ++mt)                               \
      _Pragma("unroll")                                          \
      for (int nl = 0; nl < 2; ++nl) {                           \
        acc[mt][nl][0] = 0.f; acc[mt][nl][1] = 0.f;              \
        acc[mt][nl][2] = 0.f; acc[mt][nl][3] = 0.f;              \
      }                                                          \
  }

// hidden = relu(acc + b1) -> split hi/lo back into LDS (C layout -> A layout)
#define HIDDEN_TO_LDS(B1ptr)                                     \
  {                                                              \
    const float b1a = (B1ptr)[w32 + l15];                        \
    const float b1b = (B1ptr)[w32 + 16 + l15];                   \
    _Pragma("unroll")                                            \
    for (int mt = 0; mt < 8; ++mt)                               \
      _Pragma("unroll")                                          \
      for (int nl = 0; nl < 2; ++nl) {                           \
        const int col = w32 + nl * 16 + l15;                     \
        const float bb = nl ? b1b : b1a;                         \
        _Pragma("unroll")                                        \
        for (int rg = 0; rg < 4; ++rg) {                         \
          const int row = mt * 16 + q8 * 4 + rg;                 \
          const float h = fmaxf(acc[mt][nl][rg] + bb, 0.f);      \
          float rm;                                              \
          const ushort hh = bfsplit(h, &rm);                     \
          const int off = row * LSTR + col;                      \
          Sh[off] = hh;                                          \
          Sl[off] = bftrunc(rm);                                 \
        }                                                        \
      }                                                          \
  }

// stage rows [row0, row0+nrow) of row-major f32 X (stride Dd) into Sh/Sl split
#define STAGE_ROWS(Xptr)                                                       \
  {                                                                            \
    _Pragma("unroll")                                                          \
    for (int it = 0; it < 16; ++it) {                                          \
      const int i = t + NT * it;                                               \
      const int r = i >> 5;                                                    \
      const int c4 = (i & 31) << 2;                                            \
      float4 v = make_float4(0.f, 0.f, 0.f, 0.f);                              \
      if (r < nrow) v = *(const float4*)((Xptr) + (size_t)(row0 + r) * Dd + c4); \
      ushort4 hv, lv; float rm;                                                \
      hv.x = bfsplit(v.x, &rm); lv.x = bftrunc(rm);                            \
      hv.y = bfsplit(v.y, &rm); lv.y = bftrunc(rm);                            \
      hv.z = bfsplit(v.z, &rm); lv.z = bftrunc(rm);                            \
      hv.w = bfsplit(v.w, &rm); lv.w = bftrunc(rm);                            \
      *(ushort4*)(&Sh[r * LSTR + c4]) = hv;                                    \
      *(ushort4*)(&Sl[r * LSTR + c4]) = lv;                                    \
    }                                                                          \
  }

#define MFMA_PRELUDE                                             \
  const int lane = t & 63;                                       \
  const int wave = t >> 6;                                       \
  const int l15 = lane & 15;                                     \
  const int q8 = lane >> 4;                                      \
  const int w32 = wave * 32;                                     \
  const int nt0 = wave * 2;                                      \
  f32x4 acc[8][2];

// Per-direction parameter pack: packed hi bases (lo = +16384) + biases.
struct DirP {
  const ushort *u1, *u2, *p1, *p2;             // upd w1/w2, msg w1/w2 (packed)
  const float *ub1, *ub2, *pb1, *pb2;
};

// ---------------------------------------------------------------------------
// st = fnn(feat; nt), no final relu. Single direction, 391 blocks.
// ---------------------------------------------------------------------------
__global__ __launch_bounds__(NT) void st_kernel(
    const float* __restrict__ X,
    const ushort* __restrict__ W1, const ushort* __restrict__ W2,
    const float* __restrict__ B1, const float* __restrict__ B2,
    float* __restrict__ out)
{
  __shared__ __align__(16) ushort Sbuf[2 * TE * LSTR];  // 69.6 KB
  ushort* Sh = Sbuf;
  ushort* Sl = Sbuf + TE * LSTR;
  const int t = threadIdx.x;
  const int row0 = blockIdx.x * TE;
  const int rem = Nn - row0;
  const int nrow = rem < TE ? rem : TE;

  STAGE_ROWS(X);
  __syncthreads();
  MFMA_PRELUDE;
  ZERO_ACC;
  MFMA_LAYER(W1, W1 + 16384);
  __syncthreads();
  HIDDEN_TO_LDS(B1);
  __syncthreads();
  ZERO_ACC;
  MFMA_LAYER(W2, W2 + 16384);

  const float b2a = B2[w32 + l15];
  const float b2b = B2[w32 + 16 + l15];
  #pragma unroll
  for (int mt = 0; mt < 8; ++mt)
    #pragma unroll
    for (int nl = 0; nl < 2; ++nl) {
      const int col = w32 + nl * 16 + l15;
      const float bb = nl ? b2b : b2a;
      #pragma unroll
      for (int rg = 0; rg < 4; ++rg) {
        const int row = mt * 16 + q8 * 4 + rg;
        if (row < nrow)
          out[(size_t)(row0 + row) * Dd + col] = acc[mt][nl][rg] + bb;
      }
    }
}

// ---------------------------------------------------------------------------
// Round-1 msg: M = bf16(relu(fnn(st; p))) per direction. Dual grid.
// ---------------------------------------------------------------------------
__global__ __launch_bounds__(NT) void msg0_kernel(
    const float* __restrict__ st,
    ushort* __restrict__ Mf, ushort* __restrict__ Mb,
    DirP pf, DirP pb, int nhalf)
{
  __shared__ __align__(16) ushort Sbuf[2 * TE * LSTR];
  ushort* Sh = Sbuf;
  ushort* Sl = Sbuf + TE * LSTR;
  const int t = threadIdx.x;
  const int dir = blockIdx.x >= nhalf;
  const int row0 = (blockIdx.x - dir * nhalf) * TE;
  const int rem = Nn - row0;
  const int nrow = rem < TE ? rem : TE;
  const DirP P = dir ? pb : pf;
  ushort* Mout = dir ? Mb : Mf;

  STAGE_ROWS(st);
  __syncthreads();
  MFMA_PRELUDE;
  ZERO_ACC;
  MFMA_LAYER(P.p1, P.p1 + 16384);
  __syncthreads();
  HIDDEN_TO_LDS(P.pb1);
  __syncthreads();
  ZERO_ACC;
  MFMA_LAYER(P.p2, P.p2 + 16384);

  const float b2a = P.pb2[w32 + l15];
  const float b2b = P.pb2[w32 + 16 + l15];
  #pragma unroll
  for (int mt = 0; mt < 8; ++mt)
    #pragma unroll
    for (int nl = 0; nl < 2; ++nl) {
      const int col = w32 + nl * 16 + l15;
      const float bb = nl ? b2b : b2a;
      #pragma unroll
      for (int rg = 0; rg < 4; ++rg) {
        const int row = mt * 16 + q8 * 4 + rg;
        if (row < nrow)
          Mout[(size_t)(row0 + row) * Dd + col] =
              f32_to_bf16_rtn(fmaxf(acc[mt][nl][rg] + bb, 0.f));
      }
    }
}

// ---------------------------------------------------------------------------
// Fused per-round kernel, dual direction (2*391 blocks):
//   z-tile  = CSR gather-sum of bf16 Min rows (f32 accumulate, atomic-free)
//   y-tile  = st + relu(fnn(z; u)), y[sink] handling
//   DO_MSG:   M' = bf16(relu(fnn(y; p))) -> RoutM   (rounds 1,2)
//   !DO_MSG:  y -> RoutY (f32, stride/col for d_out) (final round)
//
// Phase A: 2 threads per node row, each owns 64 cols = 128 B as 8 x 16 B
// bf16 loads, edge-unrolled x2 = 16 outstanding loads per thread.
// ---------------------------------------------------------------------------
template <int DO_MSG>
__global__ __launch_bounds__(NT) void aggupdmsg_kernel(
    const ushort* __restrict__ Min_f, const ushort* __restrict__ Min_b,
    const int* __restrict__ rp_f, const int* __restrict__ rp_b,
    const int* __restrict__ col_f, const int* __restrict__ col_b,
    const float* __restrict__ st,
    ushort* __restrict__ RMf, ushort* __restrict__ RMb,
    float* __restrict__ RYf, float* __restrict__ RYb, int rstride,
    DirP pf, DirP pb, int nhalf)
{
  __shared__ __align__(16) ushort Sbuf[2 * TE * LSTR];
  ushort* Sh = Sbuf;
  ushort* Sl = Sbuf + TE * LSTR;
  const int t = threadIdx.x;
  const int dir = blockIdx.x >= nhalf;
  const int row0 = (blockIdx.x - dir * nhalf) * TE;
  const int rem = Nn - row0;
  const int nrow = rem < TE ? rem : TE;
  const DirP P = dir ? pb : pf;
  const ushort* Min = dir ? Min_b : Min_f;
  const int* rp = dir ? rp_b : rp_f;
  const int* col = dir ? col_b : col_f;
  ushort* RoutM = dir ? RMb : RMf;
  float* RoutY = dir ? RYb : RYf;
  const int sink = dir ? 0 : (Nn - 1);

  // ---- phase A: gather-sum of bf16 M rows, f32 accumulate ----
  {
    const int nr = t >> 1;           // tile row, 2 threads per row
    const int cb = (t & 1) * 64;     // column half (elements)
    float4 za[16];
    #pragma unroll
    for (int i = 0; i < 16; ++i) za[i] = make_float4(0.f, 0.f, 0.f, 0.f);
    if (nr < nrow) {
      const int gnode = row0 + nr;
      int e = rp[gnode];
      const int ee = rp[gnode + 1];
      for (; e + 1 < ee; e += 2) {   // 16 independent 16B loads in flight
        const uint4* r0 = (const uint4*)(Min + (size_t)col[e]     * Dd + cb);
        const uint4* r1 = (const uint4*)(Min + (size_t)col[e + 1] * Dd + cb);
        uint4 v0[8], v1[8];
        #pragma unroll
        for (int i = 0; i < 8; ++i) v0[i] = r0[i];
        #pragma unroll
        for (int i = 0; i < 8; ++i) v1[i] = r1[i];
        #pragma unroll
        for (int i = 0; i < 8; ++i) {
          acc8(v0[i], za[2 * i], za[2 * i + 1]);
          acc8(v1[i], za[2 * i], za[2 * i + 1]);
        }
      }
      if (e < ee) {
        const uint4* r0 = (const uint4*)(Min + (size_t)col[e] * Dd + cb);
        #pragma unroll
        for (int i = 0; i < 8; ++i) acc8(r0[i], za[2 * i], za[2 * i + 1]);
      }
    }
    #pragma unroll
    for (int i = 0; i < 16; ++i) {
      ushort4 hv, lv; float rm;
      hv.x = bfsplit(za[i].x, &rm); lv.x = bftrunc(rm);
      hv.y = bfsplit(za[i].y, &rm); lv.y = bftrunc(rm);
      hv.z = bfsplit(za[i].z, &rm); lv.z = bftrunc(rm);
      hv.w = bfsplit(za[i].w, &rm); lv.w = bftrunc(rm);
      const int c4 = cb + i * 4;
      *(ushort4*)(&Sh[nr * LSTR + c4]) = hv;
      *(ushort4*)(&Sl[nr * LSTR + c4]) = lv;
    }
  }
  __syncthreads();

  MFMA_PRELUDE;

  // ---- phase B: update MLP ----
  ZERO_ACC;
  MFMA_LAYER(P.u1, P.u1 + 16384);
  __syncthreads();
  HIDDEN_TO_LDS(P.ub1);
  __syncthreads();
  ZERO_ACC;
  MFMA_LAYER(P.u2, P.u2 + 16384);

  // y = st + relu(acc + ub2), y[sink-row contribution] zeroed
  {
    const float b2a = P.ub2[w32 + l15];
    const float b2b = P.ub2[w32 + 16 + l15];
    if (DO_MSG) __syncthreads();  // all hidden reads done before overwrite
    #pragma unroll
    for (int mt = 0; mt < 8; ++mt)
      #pragma unroll
      for (int nl = 0; nl < 2; ++nl) {
        const int col = w32 + nl * 16 + l15;
        const float bb = nl ? b2b : b2a;
        #pragma unroll
        for (int rg = 0; rg < 4; ++rg) {
          const int row = mt * 16 + q8 * 4 + rg;
          float v = 0.f;
          if (row < nrow) {
            const int gr = row0 + row;
            v = fmaxf(acc[mt][nl][rg] + bb, 0.f);
            if (gr == sink) v = 0.f;
            v += st[(size_t)gr * Dd + col];
          }
          if (DO_MSG) {
            float rm;
            const ushort hh = bfsplit(v, &rm);
            const int off = row * LSTR + col;
            Sh[off] = hh;
            Sl[off] = bftrunc(rm);
          } else if (row < nrow) {
            RoutY[(size_t)(row0 + row) * rstride + col] = v;
          }
        }
      }
  }

  if (DO_MSG) {
    __syncthreads();
    // ---- phase C: msg MLP on y-tile ----
    ZERO_ACC;
    MFMA_LAYER(P.p1, P.p1 + 16384);
    __syncthreads();
    HIDDEN_TO_LDS(P.pb1);
    __syncthreads();
    ZERO_ACC;
    MFMA_LAYER(P.p2, P.p2 + 16384);

    const float b2a = P.pb2[w32 + l15];
    const float b2b = P.pb2[w32 + 16 + l15];
    #pragma unroll
    for (int mt = 0; mt < 8; ++mt)
      #pragma unroll
      for (int nl = 0; nl < 2; ++nl) {
        const int col = w32 + nl * 16 + l15;
        const float bb = nl ? b2b : b2a;
        #pragma unroll
        for (int rg = 0; rg < 4; ++rg) {
          const int row = mt * 16 + q8 * 4 + rg;
          if (row < nrow)
            RoutM[(size_t)(row0 + row) * Dd + col] =
                f32_to_bf16_rtn(fmaxf(acc[mt][nl][rg] + bb, 0.f));
        }
      }
  }
}

// ---------------------------------------------------------------------------
// Weight packing: matrices -> B-fragment order, split hi/lo.
// Slot = WSLOT ushorts: hi[16384], lo[16384]. id = ((nt*4+ch)*64+lane)*8+j
// maps to W[k][n]: k = ch*32+(lane>>4)*8+j, n = nt*16+(lane&15).
// ---------------------------------------------------------------------------
struct WPtrs { const float* w[10]; };

__global__ void pack_w_kernel(WPtrs P, ushort* __restrict__ out)
{
  const int id = blockIdx.x * blockDim.x + threadIdx.x;  // 0..16383
  const int mat = blockIdx.y;
  const int j = id & 7;
  const int lane = (id >> 3) & 63;
  const int ch = (id >> 9) & 3;
  const int nt = id >> 11;
  const int k = ch * 32 + (lane >> 4) * 8 + j;
  const int n = nt * 16 + (lane & 15);
  const float x = P.w[mat][k * Dd + n];
  float rm;
  const ushort h = bfsplit(x, &rm);
  out[(size_t)mat * WSLOT + id] = h;
  out[(size_t)mat * WSLOT + 16384 + id] = bftrunc(rm);
}

// ---------------------------------------------------------------------------
// CSR build: histogram -> single-block scan (x2, cur aliases deg) -> fill
// ---------------------------------------------------------------------------
__global__ void hist_kernel(const int* __restrict__ src, const int* __restrict__ dst,
                            int* __restrict__ deg_f, int* __restrict__ deg_b, int e)
{
  const int i = blockIdx.x * blockDim.x + threadIdx.x;
  if (i < e) {
    atomicAdd(&deg_f[dst[i]], 1);
    atomicAdd(&deg_b[src[i]], 1);
  }
}

__global__ __launch_bounds__(1024) void scan_kernel(
    const int* deg0, int* rp0, int* cur0,
    const int* deg1, int* rp1, int* cur1, int n)
{
  const int* deg = blockIdx.x ? deg1 : deg0;
  int* rp  = blockIdx.x ? rp1  : rp0;
  int* cur = blockIdx.x ? cur1 : cur0;
  __shared__ int a[1024], b[1024];
  const int t = threadIdx.x;
  int run = 0;
  for (int base = 0; base < n; base += 1024) {
    const int v = (base + t < n) ? deg[base + t] : 0;
    a[t] = v;
    __syncthreads();
    int* s = a; int* d = b;
    for (int off = 1; off < 1024; off <<= 1) {
      int x = s[t];
      if (t >= off) x += s[t - off];
      d[t] = x;
      __syncthreads();
      int* tmp = s; s = d; d = tmp;
    }
    const int incl = s[t];
    const int tot = s[1023];
    if (base + t < n) { rp[base + t] = run + incl - v; cur[base + t] = run + incl - v; }
    run += tot;
    __syncthreads();
  }
  if (t == 0) rp[n] = run;
}

// forward: col_f (src values) grouped by dst; backward: col_b (dst values)
// grouped by src.
__global__ void fill_kernel(const int* __restrict__ src, const int* __restrict__ dst,
                            int* __restrict__ cur_f, int* __restrict__ cur_b,
                            int* __restrict__ col_f, int* __restrict__ col_b, int e)
{
  const int i = blockIdx.x * blockDim.x + threadIdx.x;
  if (i < e) {
    const int s = src[i], d = dst[i];
    col_f[atomicAdd(&cur_f[d], 1)] = s;
    col_b[atomicAdd(&cur_b[s], 1)] = d;
  }
}

// ---------------------------------------------------------------------------
extern "C" void kernel_launch(void* const* d_in, const int* in_sizes, int n_in,
                              void* d_out, int out_size, void* d_ws, size_t ws_size,
                              hipStream_t stream)
{
  const float* feat = (const float*)d_in[0];
  const int*   src  = (const int*)d_in[1];
  const int*   dst  = (const int*)d_in[2];

  const float* W[5][4];
  for (int p = 0; p < 5; ++p)
    for (int q = 0; q < 4; ++q)
      W[p][q] = (const float*)d_in[3 + p * 4 + q];

  // workspace (~86 MB): st(f32) + 4x bf16 M arrays + CSR + packed weights
  float* st = (float*)d_ws;                          // [N,D] f32
  ushort* Mp_f = (ushort*)(st + (size_t)Nn * Dd);    // ping fwd [N,D] bf16
  ushort* Mp_b = Mp_f + (size_t)Nn * Dd;             // ping bwd
  ushort* Mq_f = Mp_b + (size_t)Nn * Dd;             // pong fwd
  ushort* Mq_b = Mq_f + (size_t)Nn * Dd;             // pong bwd
  int* ip       = (int*)(Mq_b + (size_t)Nn * Dd);
  int* rp_f     = ip;                 ip += Nn + 1;
  int* rp_b     = ip;                 ip += Nn + 1;
  int* deg_f    = ip;                 ip += Nn;   // cur aliases deg
  int* deg_b    = ip;                 ip += Nn;
  int* col_f    = ip;                 ip += Ee;
  int* col_b    = ip;                 ip += Ee;
  ushort* Wp = (ushort*)(((uintptr_t)ip + 63) & ~(uintptr_t)63);  // 640 KB
  float* out = (float*)d_out;                        // [N, 2D] f32

  const int nodeBlocks = (Nn + TE - 1) / TE;    // 391
  const int dualBlocks = 2 * nodeBlocks;        // 782
  const int eGrid = (Ee + NT - 1) / NT;

  // ---- pack weights ----
  WPtrs wpk;  // slots: 2p = W[p].w1, 2p+1 = W[p].w2
  for (int p = 0; p < 5; ++p) { wpk.w[2 * p] = W[p][0]; wpk.w[2 * p + 1] = W[p][2]; }
  pack_w_kernel<<<dim3(64, 10), NT, 0, stream>>>(wpk, Wp);

  // ---- CSR build ----
  hipMemsetAsync(deg_f, 0, (size_t)2 * Nn * sizeof(int), stream);
  hist_kernel<<<eGrid, NT, 0, stream>>>(src, dst, deg_f, deg_b, Ee);
  scan_kernel<<<2, 1024, 0, stream>>>(deg_f, rp_f, deg_f, deg_b, rp_b, deg_b, Nn);
  fill_kernel<<<eGrid, NT, 0, stream>>>(src, dst, deg_f, deg_b, col_f, col_b, Ee);

  #define WS(m) (Wp + (size_t)(m) * WSLOT)
  // fwd: upd = fu (p=2), msg = fp (p=1); bwd: upd = bu (p=4), msg = bp (p=3)
  DirP Pf = { WS(4), WS(5), WS(2), WS(3), W[2][1], W[2][3], W[1][1], W[1][3] };
  DirP Pb = { WS(8), WS(9), WS(6), WS(7), W[4][1], W[4][3], W[3][1], W[3][3] };

  // ---- st = fnn(feat; nt) ----
  st_kernel<<<nodeBlocks, NT, 0, stream>>>(feat, WS(0), WS(1), W[0][1], W[0][3], st);

  // ---- round 1 msg from st -> M ping (bf16) ----
  msg0_kernel<<<dualBlocks, NT, 0, stream>>>(st, Mp_f, Mp_b, Pf, Pb, nodeBlocks);

  // ---- round 1: agg+upd+msg, ping -> pong ----
  aggupdmsg_kernel<1><<<dualBlocks, NT, 0, stream>>>(
      Mp_f, Mp_b, rp_f, rp_b, col_f, col_b, st,
      Mq_f, Mq_b, nullptr, nullptr, 0, Pf, Pb, nodeBlocks);

  // ---- round 2: agg+upd+msg, pong -> ping ----
  aggupdmsg_kernel<1><<<dualBlocks, NT, 0, stream>>>(
      Mq_f, Mq_b, rp_f, rp_b, col_f, col_b, st,
      Mp_f, Mp_b, nullptr, nullptr, 0, Pf, Pb, nodeBlocks);

  // ---- round 3 (final): agg+upd, ping -> y into out column-halves ----
  aggupdmsg_kernel<0><<<dualBlocks, NT, 0, stream>>>(
      Mp_f, Mp_b, rp_f, rp_b, col_f, col_b, st,
      nullptr, nullptr, out, out + Dd, 2 * Dd, Pf, Pb, nodeBlocks);

  #undef WS
}

// Round 9
// 716.965 us; speedup vs baseline: 1.9726x; 1.5060x over previous
//
#include <hip/hip_runtime.h>

// Problem constants (reference: N=50000 nodes, E=800000 edges, D=128, K=3)
#define Nn 50000
#define Ee 800000
#define Dd 128
#define Kk 3
#define TE 64    // rows per block tile (34.8 KB LDS -> 4 blocks/CU)
#define NT 256   // threads per block (4 waves)

// LDS bf16 tile row stride (ushorts): 128 + 8 pad
#define LSTR 136
// Per-matrix packed-weight slot: hi[16384] + lo[16384] ushorts
#define WSLOT 32768
#define NBLK 196  // scan blocks: ceil(Nn/256)

typedef short sh8 __attribute__((ext_vector_type(8)));    // 8 bf16 (4 VGPRs)
typedef float f32x4 __attribute__((ext_vector_type(4)));  // MFMA C/D

// Split fp32 into bf16 hi (truncate) + bf16 lo (residual, truncate).
__device__ __forceinline__ ushort bfsplit(float x, float* rem) {
  const unsigned u = __float_as_uint(x);
  *rem = x - __uint_as_float(u & 0xffff0000u);
  return (ushort)(u >> 16);
}
__device__ __forceinline__ ushort bftrunc(float x) {
  return (ushort)(__float_as_uint(x) >> 16);
}
// round-to-nearest f32 -> bf16 (x >= 0, finite)
__device__ __forceinline__ ushort f32_to_bf16_rtn(float x) {
  const unsigned u = __float_as_uint(x);
  return (ushort)((u + 0x7fffu + ((u >> 16) & 1u)) >> 16);
}

// accumulate 8 bf16 packed in one uint4 into two float4 accumulators
__device__ __forceinline__ void acc8(const uint4 v, float4& a0, float4& a1) {
  a0.x += __uint_as_float(v.x << 16);
  a0.y += __uint_as_float(v.x & 0xffff0000u);
  a0.z += __uint_as_float(v.y << 16);
  a0.w += __uint_as_float(v.y & 0xffff0000u);
  a1.x += __uint_as_float(v.z << 16);
  a1.y += __uint_as_float(v.z & 0xffff0000u);
  a1.z += __uint_as_float(v.w << 16);
  a1.w += __uint_as_float(v.w & 0xffff0000u);
}

// 64x128x128 layer on MFMA 16x16x32_bf16, split-bf16 (3 products).
// Wave w owns cols [32w,32w+32); 4 m-tiles; acc[4][2].
// A frag: lane reads A[m=lane&15][k=(lane>>4)*8+j]  (ds_read_b128 from Sh/Sl)
// B frag: packed global, [((nt*4+c)*64+lane)*8+j]
#define MFMA_LAYER(WH, WL)                                                     \
  {                                                                            \
    _Pragma("unroll")                                                          \
    for (int c = 0; c < 4; ++c) {                                              \
      const sh8 bh0 = *(const sh8*)((WH) + (((nt0    ) * 4 + c) * 64 + lane) * 8); \
      const sh8 bh1 = *(const sh8*)((WH) + (((nt0 + 1) * 4 + c) * 64 + lane) * 8); \
      const sh8 bl0 = *(const sh8*)((WL) + (((nt0    ) * 4 + c) * 64 + lane) * 8); \
      const sh8 bl1 = *(const sh8*)((WL) + (((nt0 + 1) * 4 + c) * 64 + lane) * 8); \
      _Pragma("unroll")                                                        \
      for (int mt = 0; mt < 4; ++mt) {                                         \
        const int aoff = (mt * 16 + l15) * LSTR + c * 32 + q8 * 8;             \
        const sh8 ah = *(const sh8*)(Sh + aoff);                               \
        const sh8 al = *(const sh8*)(Sl + aoff);                               \
        acc[mt][0] = __builtin_amdgcn_mfma_f32_16x16x32_bf16(ah, bh0, acc[mt][0], 0, 0, 0); \
        acc[mt][1] = __builtin_amdgcn_mfma_f32_16x16x32_bf16(ah, bh1, acc[mt][1], 0, 0, 0); \
        acc[mt][0] = __builtin_amdgcn_mfma_f32_16x16x32_bf16(al, bh0, acc[mt][0], 0, 0, 0); \
        acc[mt][1] = __builtin_amdgcn_mfma_f32_16x16x32_bf16(al, bh1, acc[mt][1], 0, 0, 0); \
        acc[mt][0] = __builtin_amdgcn_mfma_f32_16x16x32_bf16(ah, bl0, acc[mt][0], 0, 0, 0); \
        acc[mt][1] = __builtin_amdgcn_mfma_f32_16x16x32_bf16(ah, bl1, acc[mt][1], 0, 0, 0); \
      }                                                                        \
    }                                                                          \
  }

#define ZERO_ACC                                                 \
  {                                                              \
    _Pragma("unroll")                                            \
    for (int mt = 0; mt < 4; ++mt)                               \
      _Pragma("unroll")                                          \
      for (int nl = 0; nl < 2; ++nl) {                           \
        acc[mt][nl][0] = 0.f; acc[mt][nl][1] = 0.f;              \
        acc[mt][nl][2] = 0.f; acc[mt][nl][3] = 0.f;              \
      }                                                          \
  }

// hidden = relu(acc + b1) -> split hi/lo back into LDS (C layout -> A layout)
#define HIDDEN_TO_LDS(B1ptr)                                     \
  {                                                              \
    const float b1a = (B1ptr)[w32 + l15];                        \
    const float b1b = (B1ptr)[w32 + 16 + l15];                   \
    _Pragma("unroll")                                            \
    for (int mt = 0; mt < 4; ++mt)                               \
      _Pragma("unroll")                                          \
      for (int nl = 0; nl < 2; ++nl) {                           \
        const int col = w32 + nl * 16 + l15;                     \
        const float bb = nl ? b1b : b1a;                         \
        _Pragma("unroll")                                        \
        for (int rg = 0; rg < 4; ++rg) {                         \
          const int row = mt * 16 + q8 * 4 + rg;                 \
          const float h = fmaxf(acc[mt][nl][rg] + bb, 0.f);      \
          float rm;                                              \
          const ushort hh = bfsplit(h, &rm);                     \
          const int off = row * LSTR + col;                      \
          Sh[off] = hh;                                          \
          Sl[off] = bftrunc(rm);                                 \
        }                                                        \
      }                                                          \
  }

// stc (C-layout f32, bias included, signed) -> split into LDS A-layout
#define STC_TO_LDS                                               \
  {                                                              \
    _Pragma("unroll")                                            \
    for (int mt = 0; mt < 4; ++mt)                               \
      _Pragma("unroll")                                          \
      for (int nl = 0; nl < 2; ++nl) {                           \
        const int col = w32 + nl * 16 + l15;                     \
        _Pragma("unroll")                                        \
        for (int rg = 0; rg < 4; ++rg) {                         \
          const int row = mt * 16 + q8 * 4 + rg;                 \
          float rm;                                              \
          const ushort hh = bfsplit(stc[mt][nl][rg], &rm);       \
          const int off = row * LSTR + col;                      \
          Sh[off] = hh;                                          \
          Sl[off] = bftrunc(rm);                                 \
        }                                                        \
      }                                                          \
  }

// stage rows [row0, row0+nrow) of row-major f32 X (stride Dd) into Sh/Sl split
#define STAGE_ROWS(Xptr)                                                       \
  {                                                                            \
    _Pragma("unroll")                                                          \
    for (int it = 0; it < (TE * 32 / NT); ++it) {                              \
      const int i = t + NT * it;                                               \
      const int r = i >> 5;                                                    \
      const int c4 = (i & 31) << 2;                                            \
      float4 v = make_float4(0.f, 0.f, 0.f, 0.f);                              \
      if (r < nrow) v = *(const float4*)((Xptr) + (size_t)(row0 + r) * Dd + c4); \
      ushort4 hv, lv; float rm;                                                \
      hv.x = bfsplit(v.x, &rm); lv.x = bftrunc(rm);                            \
      hv.y = bfsplit(v.y, &rm); lv.y = bftrunc(rm);                            \
      hv.z = bfsplit(v.z, &rm); lv.z = bftrunc(rm);                            \
      hv.w = bfsplit(v.w, &rm); lv.w = bftrunc(rm);                            \
      *(ushort4*)(&Sh[r * LSTR + c4]) = hv;                                    \
      *(ushort4*)(&Sl[r * LSTR + c4]) = lv;                                    \
    }                                                                          \
  }

#define MFMA_PRELUDE                                             \
  const int lane = t & 63;                                       \
  const int wave = t >> 6;                                       \
  const int l15 = lane & 15;                                     \
  const int q8 = lane >> 4;                                      \
  const int w32 = wave * 32;                                     \
  const int nt0 = wave * 2;                                      \
  f32x4 acc[4][2];

// Per-direction parameter pack: packed hi bases (lo = +16384) + biases.
struct DirP {
  const ushort *u1, *u2, *p1, *p2;             // upd w1/w2, msg w1/w2 (packed)
  const float *ub1, *ub2, *pb1, *pb2;
};

// ---------------------------------------------------------------------------
// Fused st + round-1 messages (782 blocks):
//   st = fnn(feat; nt)  (no relu) -> global, kept in regs
//   Mf = bf16(relu(fnn(st; fp))), Mb = bf16(relu(fnn(st; bp)))
// ---------------------------------------------------------------------------
__global__ __launch_bounds__(NT) void stmsg_kernel(
    const float* __restrict__ X,
    const ushort* __restrict__ Wn1, const ushort* __restrict__ Wn2,
    const float* __restrict__ Bn1, const float* __restrict__ Bn2,
    DirP pf, DirP pb,
    float* __restrict__ st, ushort* __restrict__ Mf, ushort* __restrict__ Mb)
{
  __shared__ __align__(16) ushort Sbuf[2 * TE * LSTR];  // 34.8 KB
  ushort* Sh = Sbuf;
  ushort* Sl = Sbuf + TE * LSTR;
  const int t = threadIdx.x;
  const int row0 = blockIdx.x * TE;
  const int rem = Nn - row0;
  const int nrow = rem < TE ? rem : TE;

  STAGE_ROWS(X);
  __syncthreads();
  MFMA_PRELUDE;

  // ---- nt MLP -> stc ----
  ZERO_ACC;
  MFMA_LAYER(Wn1, Wn1 + 16384);
  __syncthreads();
  HIDDEN_TO_LDS(Bn1);
  __syncthreads();
  ZERO_ACC;
  MFMA_LAYER(Wn2, Wn2 + 16384);

  float stc[4][2][4];
  {
    const float b2a = Bn2[w32 + l15];
    const float b2b = Bn2[w32 + 16 + l15];
    #pragma unroll
    for (int mt = 0; mt < 4; ++mt)
      #pragma unroll
      for (int nl = 0; nl < 2; ++nl) {
        const int col = w32 + nl * 16 + l15;
        const float bb = nl ? b2b : b2a;
        #pragma unroll
        for (int rg = 0; rg < 4; ++rg) {
          const int row = mt * 16 + q8 * 4 + rg;
          const float v = acc[mt][nl][rg] + bb;
          stc[mt][nl][rg] = v;
          if (row < nrow) st[(size_t)(row0 + row) * Dd + col] = v;
        }
      }
  }
  __syncthreads();  // hidden tile fully consumed

  // ---- fwd msg MLP on stc ----
  STC_TO_LDS;
  __syncthreads();
  ZERO_ACC;
  MFMA_LAYER(pf.p1, pf.p1 + 16384);
  __syncthreads();
  HIDDEN_TO_LDS(pf.pb1);
  __syncthreads();
  ZERO_ACC;
  MFMA_LAYER(pf.p2, pf.p2 + 16384);
  {
    const float b2a = pf.pb2[w32 + l15];
    const float b2b = pf.pb2[w32 + 16 + l15];
    #pragma unroll
    for (int mt = 0; mt < 4; ++mt)
      #pragma unroll
      for (int nl = 0; nl < 2; ++nl) {
        const int col = w32 + nl * 16 + l15;
        const float bb = nl ? b2b : b2a;
        #pragma unroll
        for (int rg = 0; rg < 4; ++rg) {
          const int row = mt * 16 + q8 * 4 + rg;
          if (row < nrow)
            Mf[(size_t)(row0 + row) * Dd + col] =
                f32_to_bf16_rtn(fmaxf(acc[mt][nl][rg] + bb, 0.f));
        }
      }
  }
  __syncthreads();

  // ---- bwd msg MLP on stc ----
  STC_TO_LDS;
  __syncthreads();
  ZERO_ACC;
  MFMA_LAYER(pb.p1, pb.p1 + 16384);
  __syncthreads();
  HIDDEN_TO_LDS(pb.pb1);
  __syncthreads();
  ZERO_ACC;
  MFMA_LAYER(pb.p2, pb.p2 + 16384);
  {
    const float b2a = pb.pb2[w32 + l15];
    const float b2b = pb.pb2[w32 + 16 + l15];
    #pragma unroll
    for (int mt = 0; mt < 4; ++mt)
      #pragma unroll
      for (int nl = 0; nl < 2; ++nl) {
        const int col = w32 + nl * 16 + l15;
        const float bb = nl ? b2b : b2a;
        #pragma unroll
        for (int rg = 0; rg < 4; ++rg) {
          const int row = mt * 16 + q8 * 4 + rg;
          if (row < nrow)
            Mb[(size_t)(row0 + row) * Dd + col] =
                f32_to_bf16_rtn(fmaxf(acc[mt][nl][rg] + bb, 0.f));
        }
      }
  }
}

// ---------------------------------------------------------------------------
// Fused per-round kernel, dual direction (2*782 blocks):
//   z-tile  = CSR gather-sum of bf16 Min rows (f32 accumulate, atomic-free)
//   y-tile  = st + relu(fnn(z; u)), y[sink] handling
//   DO_MSG:   M' = bf16(relu(fnn(y; p))) -> RoutM   (rounds 1,2)
//   !DO_MSG:  y -> RoutY (f32, stride/col for d_out) (final round)
//
// Phase A: 4 threads per node row; each owns 32 cols = one full 64 B line
// per edge-row; edge-unrolled x4 = 16 outstanding 16 B loads per thread.
// ---------------------------------------------------------------------------
template <int DO_MSG>
__global__ __launch_bounds__(NT) void aggupdmsg_kernel(
    const ushort* __restrict__ Min_f, const ushort* __restrict__ Min_b,
    const int* __restrict__ rp_f, const int* __restrict__ rp_b,
    const int* __restrict__ col_f, const int* __restrict__ col_b,
    const float* __restrict__ st,
    ushort* __restrict__ RMf, ushort* __restrict__ RMb,
    float* __restrict__ RYf, float* __restrict__ RYb, int rstride,
    DirP pf, DirP pb, int nhalf)
{
  __shared__ __align__(16) ushort Sbuf[2 * TE * LSTR];  // 34.8 KB
  ushort* Sh = Sbuf;
  ushort* Sl = Sbuf + TE * LSTR;
  const int t = threadIdx.x;
  const int dir = blockIdx.x >= nhalf;
  const int row0 = (blockIdx.x - dir * nhalf) * TE;
  const int rem = Nn - row0;
  const int nrow = rem < TE ? rem : TE;
  const DirP P = dir ? pb : pf;
  const ushort* Min = dir ? Min_b : Min_f;
  const int* rp = dir ? rp_b : rp_f;
  const int* col = dir ? col_b : col_f;
  ushort* RoutM = dir ? RMb : RMf;
  float* RoutY = dir ? RYb : RYf;
  const int sink = dir ? 0 : (Nn - 1);

  // ---- phase A: gather-sum of bf16 M rows, f32 accumulate ----
  {
    const int nr = t >> 2;           // tile row, 4 threads per row
    const int cb = (t & 3) << 5;     // column base (32 cols = 64 B line)
    float4 za[8];
    #pragma unroll
    for (int i = 0; i < 8; ++i) za[i] = make_float4(0.f, 0.f, 0.f, 0.f);
    if (nr < nrow) {
      const int gnode = row0 + nr;
      int e = rp[gnode];
      const int ee = rp[gnode + 1];
      for (; e + 3 < ee; e += 4) {   // 16 independent 16B loads in flight
        const uint4* r0 = (const uint4*)(Min + (size_t)col[e]     * Dd + cb);
        const uint4* r1 = (const uint4*)(Min + (size_t)col[e + 1] * Dd + cb);
        const uint4* r2 = (const uint4*)(Min + (size_t)col[e + 2] * Dd + cb);
        const uint4* r3 = (const uint4*)(Min + (size_t)col[e + 3] * Dd + cb);
        uint4 v0[4], v1[4], v2[4], v3[4];
        #pragma unroll
        for (int i = 0; i < 4; ++i) v0[i] = r0[i];
        #pragma unroll
        for (int i = 0; i < 4; ++i) v1[i] = r1[i];
        #pragma unroll
        for (int i = 0; i < 4; ++i) v2[i] = r2[i];
        #pragma unroll
        for (int i = 0; i < 4; ++i) v3[i] = r3[i];
        #pragma unroll
        for (int i = 0; i < 4; ++i) {
          acc8(v0[i], za[2 * i], za[2 * i + 1]);
          acc8(v1[i], za[2 * i], za[2 * i + 1]);
          acc8(v2[i], za[2 * i], za[2 * i + 1]);
          acc8(v3[i], za[2 * i], za[2 * i + 1]);
        }
      }
      for (; e < ee; ++e) {
        const uint4* r0 = (const uint4*)(Min + (size_t)col[e] * Dd + cb);
        #pragma unroll
        for (int i = 0; i < 4; ++i) acc8(r0[i], za[2 * i], za[2 * i + 1]);
      }
    }
    #pragma unroll
    for (int i = 0; i < 8; ++i) {
      ushort4 hv, lv; float rm;
      hv.x = bfsplit(za[i].x, &rm); lv.x = bftrunc(rm);
      hv.y = bfsplit(za[i].y, &rm); lv.y = bftrunc(rm);
      hv.z = bfsplit(za[i].z, &rm); lv.z = bftrunc(rm);
      hv.w = bfsplit(za[i].w, &rm); lv.w = bftrunc(rm);
      const int c4 = cb + i * 4;
      *(ushort4*)(&Sh[nr * LSTR + c4]) = hv;
      *(ushort4*)(&Sl[nr * LSTR + c4]) = lv;
    }
  }
  __syncthreads();

  MFMA_PRELUDE;

  // ---- phase B: update MLP ----
  ZERO_ACC;
  MFMA_LAYER(P.u1, P.u1 + 16384);
  __syncthreads();
  HIDDEN_TO_LDS(P.ub1);
  __syncthreads();
  ZERO_ACC;
  MFMA_LAYER(P.u2, P.u2 + 16384);

  // y = st + relu(acc + ub2), y[sink-row contribution] zeroed
  {
    const float b2a = P.ub2[w32 + l15];
    const float b2b = P.ub2[w32 + 16 + l15];
    if (DO_MSG) __syncthreads();  // all hidden reads done before overwrite
    #pragma unroll
    for (int mt = 0; mt < 4; ++mt)
      #pragma unroll
      for (int nl = 0; nl < 2; ++nl) {
        const int col = w32 + nl * 16 + l15;
        const float bb = nl ? b2b : b2a;
        #pragma unroll
        for (int rg = 0; rg < 4; ++rg) {
          const int row = mt * 16 + q8 * 4 + rg;
          float v = 0.f;
          if (row < nrow) {
            const int gr = row0 + row;
            v = fmaxf(acc[mt][nl][rg] + bb, 0.f);
            if (gr == sink) v = 0.f;
            v += st[(size_t)gr * Dd + col];
          }
          if (DO_MSG) {
            float rm;
            const ushort hh = bfsplit(v, &rm);
            const int off = row * LSTR + col;
            Sh[off] = hh;
            Sl[off] = bftrunc(rm);
          } else if (row < nrow) {
            RoutY[(size_t)(row0 + row) * rstride + col] = v;
          }
        }
      }
  }

  if (DO_MSG) {
    __syncthreads();
    // ---- phase C: msg MLP on y-tile ----
    ZERO_ACC;
    MFMA_LAYER(P.p1, P.p1 + 16384);
    __syncthreads();
    HIDDEN_TO_LDS(P.pb1);
    __syncthreads();
    ZERO_ACC;
    MFMA_LAYER(P.p2, P.p2 + 16384);

    const float b2a = P.pb2[w32 + l15];
    const float b2b = P.pb2[w32 + 16 + l15];
    #pragma unroll
    for (int mt = 0; mt < 4; ++mt)
      #pragma unroll
      for (int nl = 0; nl < 2; ++nl) {
        const int col = w32 + nl * 16 + l15;
        const float bb = nl ? b2b : b2a;
        #pragma unroll
        for (int rg = 0; rg < 4; ++rg) {
          const int row = mt * 16 + q8 * 4 + rg;
          if (row < nrow)
            RoutM[(size_t)(row0 + row) * Dd + col] =
                f32_to_bf16_rtn(fmaxf(acc[mt][nl][rg] + bb, 0.f));
        }
      }
  }
}

// ---------------------------------------------------------------------------
// Weight packing: matrices -> B-fragment order, split hi/lo.
// ---------------------------------------------------------------------------
struct WPtrs { const float* w[10]; };

__global__ void pack_w_kernel(WPtrs P, ushort* __restrict__ out)
{
  const int id = blockIdx.x * blockDim.x + threadIdx.x;  // 0..16383
  const int mat = blockIdx.y;
  const int j = id & 7;
  const int lane = (id >> 3) & 63;
  const int ch = (id >> 9) & 3;
  const int nt = id >> 11;
  const int k = ch * 32 + (lane >> 4) * 8 + j;
  const int n = nt * 16 + (lane & 15);
  const float x = P.w[mat][k * Dd + n];
  float rm;
  const ushort h = bfsplit(x, &rm);
  out[(size_t)mat * WSLOT + id] = h;
  out[(size_t)mat * WSLOT + 16384 + id] = bftrunc(rm);
}

// ---------------------------------------------------------------------------
// CSR build: histogram -> parallel 3-pass scan -> fill
// deg_f/deg_b contiguous (2*Nn); rp_f/rp_b contiguous (2*(Nn+1));
// cur aliases deg (each element read-then-written by the same thread).
// ---------------------------------------------------------------------------
__global__ void hist_kernel(const int* __restrict__ src, const int* __restrict__ dst,
                            int* __restrict__ deg_f, int* __restrict__ deg_b, int e)
{
  const int i = blockIdx.x * blockDim.x + threadIdx.x;
  if (i < e) {
    atomicAdd(&deg_f[dst[i]], 1);
    atomicAdd(&deg_b[src[i]], 1);
  }
}

__global__ __launch_bounds__(256) void scan_part(const int* __restrict__ deg,
                                                 int* __restrict__ bsum, int n)
{
  const int y = blockIdx.y;
  const int i = blockIdx.x * 256 + threadIdx.x;
  __shared__ int s[256];
  s[threadIdx.x] = (i < n) ? deg[y * n + i] : 0;
  __syncthreads();
  for (int off = 128; off > 0; off >>= 1) {
    if (threadIdx.x < off) s[threadIdx.x] += s[threadIdx.x + off];
    __syncthreads();
  }
  if (threadIdx.x == 0) bsum[y * NBLK + blockIdx.x] = s[0];
}

__global__ __launch_bounds__(256) void scan_tops(int* __restrict__ bsum,
                                                 int* __restrict__ rp, int n)
{
  __shared__ int s[256];
  const int t = threadIdx.x;
  for (int y = 0; y < 2; ++y) {
    const int v = (t < NBLK) ? bsum[y * NBLK + t] : 0;
    s[t] = v;
    __syncthreads();
    for (int off = 1; off < 256; off <<= 1) {
      int x = s[t];
      if (t >= off) x += s[t - off];
      __syncthreads();
      s[t] = x;
      __syncthreads();
    }
    if (t < NBLK) bsum[y * NBLK + t] = s[t] - v;  // exclusive
    if (t == NBLK - 1) rp[y * (n + 1) + n] = s[t];  // total
    __syncthreads();
  }
}

__global__ __launch_bounds__(256) void scan_fin(int* __restrict__ deg,
                                                const int* __restrict__ bsum,
                                                int* __restrict__ rp, int n)
{
  const int y = blockIdx.y;
  const int i = blockIdx.x * 256 + threadIdx.x;
  __shared__ int s[256];
  const int v = (i < n) ? deg[y * n + i] : 0;
  s[threadIdx.x] = v;
  __syncthreads();
  for (int off = 1; off < 256; off <<= 1) {
    int x = s[threadIdx.x];
    if (threadIdx.x >= off) x += s[threadIdx.x - off];
    __syncthreads();
    s[threadIdx.x] = x;
    __syncthreads();
  }
  if (i < n) {
    const int excl = bsum[y * NBLK + blockIdx.x] + s[threadIdx.x] - v;
    rp[y * (n + 1) + i] = excl;
    deg[y * n + i] = excl;  // becomes cur for fill
  }
}

__global__ void fill_kernel(const int* __restrict__ src, const int* __restrict__ dst,
                            int* __restrict__ cur_f, int* __restrict__ cur_b,
                            int* __restrict__ col_f, int* __restrict__ col_b, int e)
{
  const int i = blockIdx.x * blockDim.x + threadIdx.x;
  if (i < e) {
    const int s = src[i], d = dst[i];
    col_f[atomicAdd(&cur_f[d], 1)] = s;
    col_b[atomicAdd(&cur_b[s], 1)] = d;
  }
}

// ---------------------------------------------------------------------------
extern "C" void kernel_launch(void* const* d_in, const int* in_sizes, int n_in,
                              void* d_out, int out_size, void* d_ws, size_t ws_size,
                              hipStream_t stream)
{
  const float* feat = (const float*)d_in[0];
  const int*   src  = (const int*)d_in[1];
  const int*   dst  = (const int*)d_in[2];

  const float* W[5][4];
  for (int p = 0; p < 5; ++p)
    for (int q = 0; q < 4; ++q)
      W[p][q] = (const float*)d_in[3 + p * 4 + q];

  // workspace (~85 MB): st(f32) + 4x bf16 M arrays + CSR + packed weights
  float* st = (float*)d_ws;                          // [N,D] f32
  ushort* Mp_f = (ushort*)(st + (size_t)Nn * Dd);    // ping fwd [N,D] bf16
  ushort* Mp_b = Mp_f + (size_t)Nn * Dd;             // ping bwd
  ushort* Mq_f = Mp_b + (size_t)Nn * Dd;             // pong fwd
  ushort* Mq_b = Mq_f + (size_t)Nn * Dd;             // pong bwd
  int* ip       = (int*)(Mq_b + (size_t)Nn * Dd);
  int* rp_f     = ip;                 ip += Nn + 1;  // rp_b contiguous after
  int* rp_b     = ip;                 ip += Nn + 1;
  int* deg_f    = ip;                 ip += Nn;      // cur aliases deg
  int* deg_b    = ip;                 ip += Nn;
  int* col_f    = ip;                 ip += Ee;
  int* col_b    = ip;                 ip += Ee;
  int* bsum     = ip;                 ip += 2 * NBLK;
  ushort* Wp = (ushort*)(((uintptr_t)ip + 63) & ~(uintptr_t)63);  // 640 KB
  float* out = (float*)d_out;                        // [N, 2D] f32

  const int nodeBlocks = (Nn + TE - 1) / TE;    // 782
  const int dualBlocks = 2 * nodeBlocks;        // 1564
  const int eGrid = (Ee + NT - 1) / NT;

  // ---- pack weights ----
  WPtrs wpk;  // slots: 2p = W[p].w1, 2p+1 = W[p].w2
  for (int p = 0; p < 5; ++p) { wpk.w[2 * p] = W[p][0]; wpk.w[2 * p + 1] = W[p][2]; }
  pack_w_kernel<<<dim3(64, 10), NT, 0, stream>>>(wpk, Wp);

  // ---- CSR build ----
  hipMemsetAsync(deg_f, 0, (size_t)2 * Nn * sizeof(int), stream);
  hist_kernel<<<eGrid, NT, 0, stream>>>(src, dst, deg_f, deg_b, Ee);
  scan_part<<<dim3(NBLK, 2), 256, 0, stream>>>(deg_f, bsum, Nn);
  scan_tops<<<1, 256, 0, stream>>>(bsum, rp_f, Nn);
  scan_fin<<<dim3(NBLK, 2), 256, 0, stream>>>(deg_f, bsum, rp_f, Nn);
  fill_kernel<<<eGrid, NT, 0, stream>>>(src, dst, deg_f, deg_b, col_f, col_b, Ee);

  #define WS(m) (Wp + (size_t)(m) * WSLOT)
  // fwd: upd = fu (p=2), msg = fp (p=1); bwd: upd = bu (p=4), msg = bp (p=3)
  DirP Pf = { WS(4), WS(5), WS(2), WS(3), W[2][1], W[2][3], W[1][1], W[1][3] };
  DirP Pb = { WS(8), WS(9), WS(6), WS(7), W[4][1], W[4][3], W[3][1], W[3][3] };

  // ---- fused st + round-1 messages ----
  stmsg_kernel<<<nodeBlocks, NT, 0, stream>>>(
      feat, WS(0), WS(1), W[0][1], W[0][3], Pf, Pb, st, Mp_f, Mp_b);

  // ---- round 1: agg+upd+msg, ping -> pong ----
  aggupdmsg_kernel<1><<<dualBlocks, NT, 0, stream>>>(
      Mp_f, Mp_b, rp_f, rp_b, col_f, col_b, st,
      Mq_f, Mq_b, nullptr, nullptr, 0, Pf, Pb, nodeBlocks);

  // ---- round 2: agg+upd+msg, pong -> ping ----
  aggupdmsg_kernel<1><<<dualBlocks, NT, 0, stream>>>(
      Mq_f, Mq_b, rp_f, rp_b, col_f, col_b, st,
      Mp_f, Mp_b, nullptr, nullptr, 0, Pf, Pb, nodeBlocks);

  // ---- round 3 (final): agg+upd, ping -> y into out column-halves ----
  aggupdmsg_kernel<0><<<dualBlocks, NT, 0, stream>>>(
      Mp_f, Mp_b, rp_f, rp_b, col_f, col_b, st,
      nullptr, nullptr, out, out + Dd, 2 * Dd, Pf, Pb, nodeBlocks);

  #undef WS
}